// Round 1
// baseline (834.579 us; speedup 1.0000x reference)
//
#include <hip/hip_runtime.h>
#include <stdint.h>
#include <stddef.h>

#define BATCH 65536
#define DIN   256
#define HDIM  512
#define KDIM  768           // Din + H
#define NDIM  2048          // 4*H, gate-interleaved packing
#define HN_ELEMS (BATCH * HDIM)   // 33554432 floats per output tensor

using f32x4 = __attribute__((ext_vector_type(4))) float;
using s16x8 = __attribute__((ext_vector_type(8))) short;
using u16x8 = __attribute__((ext_vector_type(8))) unsigned short;

__device__ __forceinline__ unsigned short f2bf(float f) {
    union { float f; unsigned u; } v; v.f = f;
    unsigned r = v.u + 0x7fffu + ((v.u >> 16) & 1u);   // RNE
    return (unsigned short)(r >> 16);
}

// ---------------------------------------------------------------------------
// Pack A = [x | h_old] as bf16 [BATCH, 768], row-major. 8 cols per thread.
// 65536 * 96 segments = 6291456 threads = 24576 blocks * 256.
// ---------------------------------------------------------------------------
__global__ __launch_bounds__(256) void pack_a_kernel(
    const float* __restrict__ x, const float* __restrict__ h,
    unsigned short* __restrict__ aPack)
{
    int idx = blockIdx.x * 256 + threadIdx.x;
    int row = idx / 96;
    int seg = idx - row * 96;                  // 0..95, each = 8 cols
    const float* src = (seg < 32) ? (x + (size_t)row * DIN  + seg * 8)
                                  : (h + (size_t)row * HDIM + (seg - 32) * 8);
    const f32x4* s4 = (const f32x4*)src;
    f32x4 v0 = s4[0], v1 = s4[1];
    u16x8 o;
    o[0] = f2bf(v0[0]); o[1] = f2bf(v0[1]); o[2] = f2bf(v0[2]); o[3] = f2bf(v0[3]);
    o[4] = f2bf(v1[0]); o[5] = f2bf(v1[1]); o[6] = f2bf(v1[2]); o[7] = f2bf(v1[3]);
    *(u16x8*)(aPack + (size_t)row * KDIM + seg * 8) = o;
}

// ---------------------------------------------------------------------------
// Pack weights as bf16 B^T layout: wPack[n][k], n in [0,2048), k in [0,768).
// Column permutation: n = (h>>4)*64 + g*16 + (h&15)  <=>  given n:
//   g = (n>>4)&3 ; h = ((n>>6)<<4) | (n&15)
// B[k][n] = (k < 256) ? U[g][k][h] : W[g][k-256][h]
// 768*2048 = 1572864 threads = 6144 blocks * 256. t = k*2048 + n so reads
// of U/W are coalesced along h.
// ---------------------------------------------------------------------------
__global__ __launch_bounds__(256) void pack_w_kernel(
    const float* __restrict__ U, const float* __restrict__ W,
    unsigned short* __restrict__ wPack)
{
    int t = blockIdx.x * 256 + threadIdx.x;
    int k = t >> 11;            // / 2048
    int n = t & 2047;
    int g = (n >> 4) & 3;
    int h = ((n >> 6) << 4) | (n & 15);
    float v = (k < DIN) ? U[((size_t)g * DIN  + k)        * HDIM + h]
                        : W[((size_t)g * HDIM + (k - DIN)) * HDIM + h];
    wPack[(size_t)n * KDIM + k] = f2bf(v);
}

__global__ __launch_bounds__(256) void pack_bias_kernel(
    const float* __restrict__ bU, const float* __restrict__ bW,
    float* __restrict__ bias)
{
    int n = blockIdx.x * 256 + threadIdx.x;   // 2048 total
    int g = (n >> 4) & 3;
    int h = ((n >> 6) << 4) | (n & 15);
    bias[n] = bU[g * HDIM + h] + bW[g * HDIM + h];
}

// ---------------------------------------------------------------------------
// Fused GEMM + LSTM epilogue.
// C[b][n] = A[b][:] . wPack[n][:] + bias[n], tiles 128x128, BK=32,
// 256 threads = 4 waves in 2x2, each wave 64x64 via 4x4 frags of 16x16x32.
// Gate-interleaved n => wave frag-column j IS gate j at the same h.
// ---------------------------------------------------------------------------
__global__ __launch_bounds__(256) void lstm_gemm_kernel(
    const unsigned short* __restrict__ aPack,
    const unsigned short* __restrict__ wPack,
    const float* __restrict__ bias,
    const float* __restrict__ c_old,
    float* __restrict__ out)
{
    __shared__ __align__(16) unsigned short smem[8192];  // A tile 4096, B tile 4096 (ushort)

    const int tid = threadIdx.x;
    const int w   = tid >> 6;          // wave 0..3
    const int l   = tid & 63;
    const int bx  = blockIdx.x;
    const int n0  = (bx & 15) * 128;   // N fastest -> A strip L2 reuse
    const int m0  = (bx >> 4) * 128;
    const int wm  = w >> 1;            // 0..1
    const int wn  = w & 1;             // 0..1
    const int lq  = l >> 4;            // quad 0..3
    const int lc  = l & 15;

    f32x4 acc[4][4];
#pragma unroll
    for (int i = 0; i < 4; ++i)
#pragma unroll
        for (int j = 0; j < 4; ++j)
            acc[i][j] = (f32x4){0.f, 0.f, 0.f, 0.f};

    // staging: per wave per issue j: 64 lanes x 16B = 1KB; tile row = (j*4+w)*16 + l/4
    const int stg_row = w * 16 + (l >> 2);     // + j*64
    const int stg_col = (l & 3) * 8;           // bf16 element offset within 32-col row

    for (int kt = 0; kt < 24; ++kt) {
        const int k0 = kt * 32;
#pragma unroll
        for (int j = 0; j < 2; ++j) {
            const int r = stg_row + j * 64;
            const unsigned short* ga = aPack + (size_t)(m0 + r) * KDIM + k0 + stg_col;
            const unsigned short* gb = wPack + (size_t)(n0 + r) * KDIM + k0 + stg_col;
            unsigned short* la = &smem[(j * 4 + w) * 512];          // 1KB chunks
            unsigned short* lb = &smem[4096 + (j * 4 + w) * 512];
            __builtin_amdgcn_global_load_lds(
                (const __attribute__((address_space(1))) void*)ga,
                (__attribute__((address_space(3))) void*)la, 16, 0, 0);
            __builtin_amdgcn_global_load_lds(
                (const __attribute__((address_space(1))) void*)gb,
                (__attribute__((address_space(3))) void*)lb, 16, 0, 0);
        }
        __syncthreads();

        s16x8 af[4], bf[4];
#pragma unroll
        for (int i = 0; i < 4; ++i) {
            int row = wm * 64 + i * 16 + lc;
            af[i] = *(const s16x8*)&smem[row * 32 + lq * 8];
        }
#pragma unroll
        for (int j = 0; j < 4; ++j) {
            int row = wn * 64 + j * 16 + lc;
            bf[j] = *(const s16x8*)&smem[4096 + row * 32 + lq * 8];
        }
#pragma unroll
        for (int i = 0; i < 4; ++i)
#pragma unroll
            for (int j = 0; j < 4; ++j)
                acc[i][j] = __builtin_amdgcn_mfma_f32_16x16x32_bf16(af[i], bf[j], acc[i][j], 0, 0, 0);
        __syncthreads();
    }

    // Epilogue: lane holds gates i,f,o,c (j=0..3) for (row, h), h = nbase/4 + lc
    const int nbase = n0 + wn * 64;
    const int hcol  = (nbase >> 2) + lc;
    const float b0 = bias[nbase +  0 + lc];
    const float b1 = bias[nbase + 16 + lc];
    const float b2 = bias[nbase + 32 + lc];
    const float b3 = bias[nbase + 48 + lc];

#pragma unroll
    for (int i = 0; i < 4; ++i) {
        const int rowb = m0 + wm * 64 + i * 16 + lq * 4;
#pragma unroll
        for (int r = 0; r < 4; ++r) {
            const int row = rowb + r;
            const float gi = acc[i][0][r] + b0;
            const float gf = acc[i][1][r] + b1;
            const float go = acc[i][2][r] + b2;
            const float gc = acc[i][3][r] + b3;
            const float it = 1.f / (1.f + __expf(-gi));
            const float ft = 1.f / (1.f + __expf(-gf));
            const float ot = 1.f / (1.f + __expf(-go));
            const float ct = 2.f / (1.f + __expf(-2.f * gc)) - 1.f;
            const float co = c_old[(size_t)row * HDIM + hcol];
            const float cn = it * ct + ft * co;
            const float tc = 2.f / (1.f + __expf(-2.f * cn)) - 1.f;
            out[(size_t)row * HDIM + hcol] = ot * tc;                       // h_new
            out[(size_t)HN_ELEMS + (size_t)row * HDIM + hcol] = cn;        // c_new
        }
    }
}

extern "C" void kernel_launch(void* const* d_in, const int* in_sizes, int n_in,
                              void* d_out, int out_size, void* d_ws, size_t ws_size,
                              hipStream_t stream)
{
    const float* x     = (const float*)d_in[0];
    const float* h_old = (const float*)d_in[1];
    const float* c_old = (const float*)d_in[2];
    const float* U     = (const float*)d_in[3];
    const float* bU    = (const float*)d_in[4];
    const float* W     = (const float*)d_in[5];
    const float* bW    = (const float*)d_in[6];
    float* out = (float*)d_out;

    // workspace layout
    unsigned short* aPack = (unsigned short*)d_ws;                       // 96 MB
    unsigned short* wPack = (unsigned short*)((char*)d_ws + (size_t)BATCH * KDIM * 2); // 3 MB
    float* bias = (float*)((char*)wPack + (size_t)NDIM * KDIM * 2);      // 8 KB

    pack_a_kernel<<<dim3(24576), dim3(256), 0, stream>>>(x, h_old, aPack);
    pack_w_kernel<<<dim3(6144), dim3(256), 0, stream>>>(U, W, wPack);
    pack_bias_kernel<<<dim3(8), dim3(256), 0, stream>>>(bU, bW, bias);
    lstm_gemm_kernel<<<dim3(8192), dim3(256), 0, stream>>>(aPack, wPack, bias, c_old, out);
}

// Round 2
// 755.770 us; speedup vs baseline: 1.1043x; 1.1043x over previous
//
#include <hip/hip_runtime.h>
#include <stdint.h>
#include <stddef.h>

#define BATCH 65536
#define DIN   256
#define HDIM  512
#define KDIM  768           // Din + H
#define NDIM  2048          // 4*H, gate-interleaved packing
#define HN_ELEMS (BATCH * HDIM)   // 33554432 floats per output tensor

using f32x4 = __attribute__((ext_vector_type(4))) float;
using s16x8 = __attribute__((ext_vector_type(8))) short;
using u16x8 = __attribute__((ext_vector_type(8))) unsigned short;

__device__ __forceinline__ unsigned short f2bf(float f) {
    union { float f; unsigned u; } v; v.f = f;
    unsigned r = v.u + 0x7fffu + ((v.u >> 16) & 1u);   // RNE
    return (unsigned short)(r >> 16);
}

// ---------------------------------------------------------------------------
// Pack A = [x | h_old] as bf16 [BATCH, 768], row-major. 8 cols per thread.
// ---------------------------------------------------------------------------
__global__ __launch_bounds__(256) void pack_a_kernel(
    const float* __restrict__ x, const float* __restrict__ h,
    unsigned short* __restrict__ aPack)
{
    int idx = blockIdx.x * 256 + threadIdx.x;
    int row = idx / 96;
    int seg = idx - row * 96;                  // 0..95, each = 8 cols
    const float* src = (seg < 32) ? (x + (size_t)row * DIN  + seg * 8)
                                  : (h + (size_t)row * HDIM + (seg - 32) * 8);
    const f32x4* s4 = (const f32x4*)src;
    f32x4 v0 = s4[0], v1 = s4[1];
    u16x8 o;
    o[0] = f2bf(v0[0]); o[1] = f2bf(v0[1]); o[2] = f2bf(v0[2]); o[3] = f2bf(v0[3]);
    o[4] = f2bf(v1[0]); o[5] = f2bf(v1[1]); o[6] = f2bf(v1[2]); o[7] = f2bf(v1[3]);
    *(u16x8*)(aPack + (size_t)row * KDIM + seg * 8) = o;
}

// ---------------------------------------------------------------------------
// Pack weights bf16 B^T: wPack[n][k]. One thread = one (n, 8k) => coalesced
// 16B writes (old version scattered 2B stores at stride 1536B).
// n = (h>>4)*64 + g*16 + (h&15);  g=(n>>4)&3, h=((n>>6)<<4)|(n&15)
// ---------------------------------------------------------------------------
__global__ __launch_bounds__(256) void pack_w_kernel(
    const float* __restrict__ U, const float* __restrict__ W,
    unsigned short* __restrict__ wPack)
{
    int idx = blockIdx.x * 256 + threadIdx.x;   // 2048*96 = 196608 threads
    int n = idx / 96;
    int seg = idx - n * 96;
    int k0 = seg * 8;
    int g = (n >> 4) & 3;
    int h = ((n >> 6) << 4) | (n & 15);
    u16x8 o;
    if (k0 < DIN) {
        const float* src = U + ((size_t)g * DIN + k0) * HDIM + h;
#pragma unroll
        for (int kk = 0; kk < 8; ++kk) o[kk] = f2bf(src[(size_t)kk * HDIM]);
    } else {
        const float* src = W + ((size_t)g * HDIM + (k0 - DIN)) * HDIM + h;
#pragma unroll
        for (int kk = 0; kk < 8; ++kk) o[kk] = f2bf(src[(size_t)kk * HDIM]);
    }
    *(u16x8*)(wPack + (size_t)n * KDIM + k0) = o;
}

__global__ __launch_bounds__(256) void pack_bias_kernel(
    const float* __restrict__ bU, const float* __restrict__ bW,
    float* __restrict__ bias)
{
    int n = blockIdx.x * 256 + threadIdx.x;   // 2048 total
    int g = (n >> 4) & 3;
    int h = ((n >> 6) << 4) | (n & 15);
    bias[n] = bU[g * HDIM + h] + bW[g * HDIM + h];
}

// ---------------------------------------------------------------------------
// Fused GEMM + LSTM epilogue. 128x128 tile, BK=32, 4 waves 2x2 of 64x64.
// XOR bank swizzle on LDS chunk position; LDS-transposed full-line stores.
// ---------------------------------------------------------------------------
__global__ __launch_bounds__(256) void lstm_gemm_kernel(
    const unsigned short* __restrict__ aPack,
    const unsigned short* __restrict__ wPack,
    const float* __restrict__ bias,
    const float* __restrict__ c_old,
    float* __restrict__ out)
{
    __shared__ __align__(16) unsigned short smem[8192];  // 16 KB: A 8KB | B 8KB; reused by epilogue

    const int tid = threadIdx.x;
    const int w   = tid >> 6;          // wave 0..3
    const int l   = tid & 63;
    const int bx  = blockIdx.x;
    const int n0  = (bx & 15) * 128;   // N fastest -> A strip L2 reuse
    const int m0  = (bx >> 4) * 128;
    const int wm  = w >> 1;
    const int wn  = w & 1;
    const int lq  = l >> 4;            // quad 0..3
    const int lc  = l & 15;

    // ---- register prefetch: bias + c_old (consumed in epilogue) ----
    const int nbase = n0 + wn * 64;
    const int hcol  = (n0 >> 2) + wn * 16 + lc;
    const float b0 = bias[nbase +  0 + lc];
    const float b1 = bias[nbase + 16 + lc];
    const float b2 = bias[nbase + 32 + lc];
    const float b3 = bias[nbase + 48 + lc];
    float co[4][4];
#pragma unroll
    for (int i = 0; i < 4; ++i)
#pragma unroll
        for (int r = 0; r < 4; ++r)
            co[i][r] = c_old[(size_t)(m0 + wm * 64 + i * 16 + lq * 4 + r) * HDIM + hcol];

    f32x4 acc[4][4];
#pragma unroll
    for (int i = 0; i < 4; ++i)
#pragma unroll
        for (int j = 0; j < 4; ++j)
            acc[i][j] = (f32x4){0.f, 0.f, 0.f, 0.f};

    // staging: lane l writes LDS row base+(l>>2), pos (l&3). XOR swizzle:
    // LDS pos p of row r holds global chunk p ^ ((r>>2)&3); so lane fetches
    // global chunk (l&3) ^ ((l>>4)&3).
    const int stg_row = w * 16 + (l >> 2);     // + j*64
    const int stg_col = (((l & 3) ^ ((l >> 4) & 3))) * 8;
    const int swz = (lc >> 2) & 3;             // read-side swizzle

    for (int kt = 0; kt < 24; ++kt) {
        const int k0 = kt * 32;
#pragma unroll
        for (int j = 0; j < 2; ++j) {
            const int r = stg_row + j * 64;
            const unsigned short* ga = aPack + (size_t)(m0 + r) * KDIM + k0 + stg_col;
            const unsigned short* gb = wPack + (size_t)(n0 + r) * KDIM + k0 + stg_col;
            unsigned short* la = &smem[(j * 4 + w) * 512];
            unsigned short* lb = &smem[4096 + (j * 4 + w) * 512];
            __builtin_amdgcn_global_load_lds(
                (const __attribute__((address_space(1))) void*)ga,
                (__attribute__((address_space(3))) void*)la, 16, 0, 0);
            __builtin_amdgcn_global_load_lds(
                (const __attribute__((address_space(1))) void*)gb,
                (__attribute__((address_space(3))) void*)lb, 16, 0, 0);
        }
        __syncthreads();

        s16x8 af[4], bf[4];
#pragma unroll
        for (int i = 0; i < 4; ++i) {
            int row = wm * 64 + i * 16 + lc;
            af[i] = *(const s16x8*)&smem[row * 32 + (lq ^ swz) * 8];
        }
#pragma unroll
        for (int j = 0; j < 4; ++j) {
            int row = wn * 64 + j * 16 + lc;
            bf[j] = *(const s16x8*)&smem[4096 + row * 32 + (lq ^ swz) * 8];
        }
#pragma unroll
        for (int i = 0; i < 4; ++i)
#pragma unroll
            for (int j = 0; j < 4; ++j)
                acc[i][j] = __builtin_amdgcn_mfma_f32_16x16x32_bf16(af[i], bf[j], acc[i][j], 0, 0, 0);
        __syncthreads();
    }

    // ---- epilogue: lane holds gates i,f,o,c (j=0..3) for (row, hcol) ----
    // Transpose hn/cn through LDS so global stores are full 128B lines.
    // LDS tiles: [32 cols][stride 36 floats], col = wn*16+lc, rloc = wm*16+lq*4+r
    float* fsm  = (float*)smem;
    float* hn_t = fsm;            // 32*36 = 1152 floats
    float* cn_t = fsm + 1152;     // total 9216 B < 16 KB

#pragma unroll
    for (int i = 0; i < 4; ++i) {
        f32x4 hnv, cnv;
#pragma unroll
        for (int r = 0; r < 4; ++r) {
            const float gi = acc[i][0][r] + b0;
            const float gf = acc[i][1][r] + b1;
            const float go = acc[i][2][r] + b2;
            const float gc = acc[i][3][r] + b3;
            const float it = 1.f / (1.f + __expf(-gi));
            const float ft = 1.f / (1.f + __expf(-gf));
            const float ot = 1.f / (1.f + __expf(-go));
            const float ct = 2.f / (1.f + __expf(-2.f * gc)) - 1.f;
            const float cn = it * ct + ft * co[i][r];
            const float tc = 2.f / (1.f + __expf(-2.f * cn)) - 1.f;
            cnv[r] = cn;
            hnv[r] = ot * tc;
        }
        __syncthreads();   // previous chunk's phase-B reads done
        {
            const int addr = (wn * 16 + lc) * 36 + wm * 16 + lq * 4;
            *(f32x4*)&hn_t[addr] = hnv;
            *(f32x4*)&cn_t[addr] = cnv;
        }
        __syncthreads();
        // phase B: full-line coalesced stores. 8 threads/row x 32 rows.
        {
            const int rloc = tid >> 3;          // 0..31
            const int cg   = tid & 7;           // 0..7 -> 4 cols each
            const int grow = m0 + (rloc >> 4) * 64 + i * 16 + (rloc & 15);
            f32x4 hv, cv;
#pragma unroll
            for (int c = 0; c < 4; ++c) {
                hv[c] = hn_t[(cg * 4 + c) * 36 + rloc];
                cv[c] = cn_t[(cg * 4 + c) * 36 + rloc];
            }
            const size_t ob = (size_t)grow * HDIM + (n0 >> 2) + cg * 4;
            *(f32x4*)&out[ob] = hv;
            *(f32x4*)&out[(size_t)HN_ELEMS + ob] = cv;
        }
    }
}

extern "C" void kernel_launch(void* const* d_in, const int* in_sizes, int n_in,
                              void* d_out, int out_size, void* d_ws, size_t ws_size,
                              hipStream_t stream)
{
    const float* x     = (const float*)d_in[0];
    const float* h_old = (const float*)d_in[1];
    const float* c_old = (const float*)d_in[2];
    const float* U     = (const float*)d_in[3];
    const float* bU    = (const float*)d_in[4];
    const float* W     = (const float*)d_in[5];
    const float* bW    = (const float*)d_in[6];
    float* out = (float*)d_out;

    unsigned short* aPack = (unsigned short*)d_ws;                                     // 96 MB
    unsigned short* wPack = (unsigned short*)((char*)d_ws + (size_t)BATCH * KDIM * 2); // 3 MB
    float* bias = (float*)((char*)wPack + (size_t)NDIM * KDIM * 2);                    // 8 KB

    pack_a_kernel<<<dim3(24576), dim3(256), 0, stream>>>(x, h_old, aPack);
    pack_w_kernel<<<dim3(768), dim3(256), 0, stream>>>(U, W, wPack);
    pack_bias_kernel<<<dim3(8), dim3(256), 0, stream>>>(bU, bW, bias);
    lstm_gemm_kernel<<<dim3(8192), dim3(256), 0, stream>>>(aPack, wPack, bias, c_old, out);
}